// Round 12
// baseline (105.057 us; speedup 1.0000x reference)
//
#include <hip/hip_runtime.h>
#include <hip/hip_bf16.h>

#define N_ROWS 16384
#define DIM 128

constexpr float INV_T = 1.0f / 0.07f;                 // 14.2857...
constexpr float LOG2E = 1.4426950408889634f;
constexpr float C1    = INV_T * LOG2E;                // exp2 scale, folded into A
constexpr float LN2   = 0.69314718055994530942f;

typedef short bf16x8 __attribute__((ext_vector_type(8)));
typedef float f32x16 __attribute__((ext_vector_type(16)));

typedef const __attribute__((address_space(1))) void* gptr1_t;
typedef __attribute__((address_space(3))) void*       sptr3_t;

__device__ __forceinline__ ushort f2bf(float x) {
    unsigned u = __float_as_uint(x);
    u += 0x7fffu + ((u >> 16) & 1u);                  // RTNE
    return (ushort)(u >> 16);
}

// p stored PRE-TILED in B-fragment order, 32-col tiles of 8KB:
//   layout [tile32][kf8][hi2][c31 32]x(8 bf16)   (proven R11)
#define TILE_U16 4096                 /* 32 cols x 128 k = 8 KB           */
#define TILE_BYTES 8192
#define BM 256                        /* rows per block (4 waves x 64)    */
#define WROWS 64
#define COLSPLIT 8                    /* grid 512 = 2 blocks/CU, no tail  */
#define COLS_PER (N_ROWS / COLSPLIT)  /* 2048 */
#define NJT (COLS_PER / 32)           /* 64 tiles (even: accE/accO pairs) */

// ---------------------------------------------------------------------------
// Kernel 1: normalize; A scaled by C1 (exp2 fold); P written tiled (32-col);
// exact fp32 diagonal logit.  (unchanged from R11 — proven)
// ---------------------------------------------------------------------------
__global__ __launch_bounds__(256) void norm_kernel(
    const float* __restrict__ A, const float* __restrict__ P,
    ushort* __restrict__ a16, ushort* __restrict__ p16t,
    float* __restrict__ diag)
{
    int row  = blockIdx.x * 4 + (threadIdx.x >> 6);
    int lane = threadIdx.x & 63;
    float2 av = *(const float2*)(A + (size_t)row * DIM + lane * 2);
    float2 pv = *(const float2*)(P + (size_t)row * DIM + lane * 2);
    float ssa = av.x * av.x + av.y * av.y;
    float ssp = pv.x * pv.x + pv.y * pv.y;
    float dp  = av.x * pv.x + av.y * pv.y;
    #pragma unroll
    for (int m = 1; m < 64; m <<= 1) {
        ssa += __shfl_xor(ssa, m);
        ssp += __shfl_xor(ssp, m);
        dp  += __shfl_xor(dp,  m);
    }
    float ra = 1.0f / fmaxf(sqrtf(ssa), 1e-12f);
    float rp = 1.0f / fmaxf(sqrtf(ssp), 1e-12f);
    if (lane == 0) diag[row] = dp * ra * rp * INV_T;
    float sa = ra * C1;
    ushort2 a2, p2;
    a2.x = f2bf(av.x * sa); a2.y = f2bf(av.y * sa);
    p2.x = f2bf(pv.x * rp); p2.y = f2bf(pv.y * rp);
    *(ushort2*)(a16 + (size_t)row * DIM + lane * 2) = a2;
    // k = 2*lane: kf=lane>>3, hi=(lane>>2)&1, e=2*(lane&3)
    size_t off = (size_t)(row >> 5) * TILE_U16 + (lane >> 3) * 512
               + ((lane >> 2) & 1) * 256 + (row & 31) * 8 + (lane & 3) * 2;
    *(ushort2*)(p16t + off) = p2;
}

// ---------------------------------------------------------------------------
// Kernel 2: per-row sum of exp2(C1*cos - C1) via 32x32x16 bf16 MFMA.
// BARRIER-FREE per-wave pipeline: each wave owns a PRIVATE double-buffered
// 8KB tile (4 waves x 16KB = 64KB LDS/block), staged via global_load_lds,
// synchronized ONLY by per-wave counted vmcnt (in-order retirement: the
// oldest 8 outstanding loads are always the tile about to be consumed).
// Waves free-run and de-phase -> matrix pipe stays fed.
// accE/accO (static names, rule #20): exp2/add of tile j-1 issues after the
// independent MFMA cluster of tile j -> trans hides under matrix.
// REG-CAP DISCIPLINE: (256,2) ONLY — tighter caps spill (R2/R4/R6).
// ---------------------------------------------------------------------------
__global__ __launch_bounds__(256, 2) void lse_kernel(
    const ushort* __restrict__ a16, const ushort* __restrict__ p16t,
    float* __restrict__ s_accum)
{
    __shared__ __attribute__((aligned(16))) ushort btile[4][2][TILE_U16];

    int colseg = blockIdx.x & (COLSPLIT - 1);   // bid%8 = XCD -> seg pinned
    int rowblk = blockIdx.x / COLSPLIT;         // 0..63
    int wave = threadIdx.x >> 6;
    int lane = threadIdx.x & 63;
    int c31  = lane & 31, hi = lane >> 5;
    int row0 = rowblk * BM + wave * WROWS;

    // A fragments: 2 row-tiles x 8 K-frags (K=16 each), 8 bf16/lane.
    bf16x8 afrag[2][8];
    #pragma unroll
    for (int t = 0; t < 2; ++t)
        #pragma unroll
        for (int kf = 0; kf < 8; ++kf)
            afrag[t][kf] = *(const bf16x8*)(
                a16 + (size_t)(row0 + t * 32 + c31) * DIM + kf * 16 + hi * 8);

    f32x16 cinit;
    #pragma unroll
    for (int r = 0; r < 16; ++r) cinit[r] = -C1;

    float s0[16], s1[16];
    #pragma unroll
    for (int r = 0; r < 16; ++r) { s0[r] = 0.f; s1[r] = 0.f; }

    const char* seg = (const char*)p16t + (size_t)colseg * NJT * TILE_BYTES;
    char* bufA = (char*)&btile[wave][0][0];
    char* bufB = (char*)&btile[wave][1][0];
    int loff = lane * 16;

    // stage one full 8KB tile into this wave's buffer (8 x 1KB wave-loads)
    auto STAGE = [&](char* dst, int t) {
        const char* src = seg + (size_t)t * TILE_BYTES + loff;
        #pragma unroll
        for (int i = 0; i < 8; ++i)
            __builtin_amdgcn_global_load_lds(
                (gptr1_t)(src + i * 1024),
                (sptr3_t)(dst + loff + i * 1024), 16, 0, 0);
    };

    auto MFMA_TILE = [&](const char* buf, f32x16& o0, f32x16& o1) {
        const ushort* tb = (const ushort*)buf + lane * 8;
        bf16x8 b0 = *(const bf16x8*)(tb);
        __builtin_amdgcn_s_setprio(1);
        o0 = __builtin_amdgcn_mfma_f32_32x32x16_bf16(afrag[0][0], b0, cinit, 0, 0, 0);
        o1 = __builtin_amdgcn_mfma_f32_32x32x16_bf16(afrag[1][0], b0, cinit, 0, 0, 0);
        #pragma unroll
        for (int kf = 1; kf < 8; ++kf) {
            bf16x8 b = *(const bf16x8*)(tb + kf * 512);
            o0 = __builtin_amdgcn_mfma_f32_32x32x16_bf16(afrag[0][kf], b, o0, 0, 0, 0);
            o1 = __builtin_amdgcn_mfma_f32_32x32x16_bf16(afrag[1][kf], b, o1, 0, 0, 0);
        }
        __builtin_amdgcn_s_setprio(0);
    };

    auto EXPADD = [&](const f32x16& a0, const f32x16& a1) {
        #pragma unroll
        for (int r = 0; r < 16; ++r) {
            s0[r] += __builtin_amdgcn_exp2f(a0[r]);
            s1[r] += __builtin_amdgcn_exp2f(a1[r]);
        }
    };

    f32x16 accE0, accE1, accO0, accO1;

    // prologue: tiles 0 (bufA) and 1 (bufB) in flight
    STAGE(bufA, 0);
    STAGE(bufB, 1);
    asm volatile("s_waitcnt vmcnt(8)" ::: "memory");   // tile 0 landed
    MFMA_TILE(bufA, accE0, accE1);
    STAGE(bufA, 2);

    for (int m = 0; m < 31; ++m) {
        asm volatile("s_waitcnt vmcnt(8)" ::: "memory"); // tile 2m+1 landed
        MFMA_TILE(bufB, accO0, accO1);
        EXPADD(accE0, accE1);                            // exp of tile 2m
        STAGE(bufB, 2 * m + 3);
        asm volatile("s_waitcnt vmcnt(8)" ::: "memory"); // tile 2m+2 landed
        MFMA_TILE(bufA, accE0, accE1);
        EXPADD(accO0, accO1);                            // exp of tile 2m+1
        if (m < 30) STAGE(bufA, 2 * m + 4);
    }
    asm volatile("s_waitcnt vmcnt(0)" ::: "memory");     // tile 63 landed
    MFMA_TILE(bufB, accO0, accO1);
    EXPADD(accE0, accE1);                                // tile 62
    EXPADD(accO0, accO1);                                // tile 63

    // reduce each row's 32 column-lanes (within each 32-lane half), one atomic
    #pragma unroll
    for (int t = 0; t < 2; ++t)
        #pragma unroll
        for (int r = 0; r < 16; ++r) {
            float v = (t ? s1[r] : s0[r]);
            v += __shfl_xor(v, 1);
            v += __shfl_xor(v, 2);
            v += __shfl_xor(v, 4);
            v += __shfl_xor(v, 8);
            v += __shfl_xor(v, 16);
            if (c31 == 0)
                atomicAdd(&s_accum[row0 + t * 32 + (r & 3) + 8 * (r >> 2) + 4 * hi], v);
        }
}

// ---------------------------------------------------------------------------
// Kernel 3: loss = mean( ln(s_i) + 1/T - diag_i )
// ---------------------------------------------------------------------------
__global__ __launch_bounds__(1024) void finalize_kernel(
    const float* __restrict__ s_acc, const float* __restrict__ diag,
    float* __restrict__ out)
{
    float acc = 0.f;
    int t = threadIdx.x;
    #pragma unroll
    for (int i = 0; i < 4; ++i) {
        int idx = (i * 1024 + t) * 4;
        float4 sv = *(const float4*)(s_acc + idx);
        float4 dv = *(const float4*)(diag + idx);
        acc += __builtin_amdgcn_logf(sv.x) * LN2 + INV_T - dv.x;
        acc += __builtin_amdgcn_logf(sv.y) * LN2 + INV_T - dv.y;
        acc += __builtin_amdgcn_logf(sv.z) * LN2 + INV_T - dv.z;
        acc += __builtin_amdgcn_logf(sv.w) * LN2 + INV_T - dv.w;
    }
    #pragma unroll
    for (int m = 1; m < 64; m <<= 1) acc += __shfl_xor(acc, m);
    __shared__ float wsum[16];
    if ((t & 63) == 0) wsum[t >> 6] = acc;
    __syncthreads();
    if (t == 0) {
        float r = 0.f;
        #pragma unroll
        for (int i = 0; i < 16; ++i) r += wsum[i];
        out[0] = r / (float)N_ROWS;
    }
}

// ---------------------------------------------------------------------------
extern "C" void kernel_launch(void* const* d_in, const int* in_sizes, int n_in,
                              void* d_out, int out_size, void* d_ws, size_t ws_size,
                              hipStream_t stream)
{
    const float* A = (const float*)d_in[0];
    const float* P = (const float*)d_in[1];
    float* out = (float*)d_out;

    char* ws = (char*)d_ws;
    ushort* a16  = (ushort*)ws;                                   // 4 MB
    ushort* p16t = (ushort*)(ws + (size_t)4 * 1024 * 1024);       // 4 MB tiled
    float*  diag = (float*)(ws + (size_t)8 * 1024 * 1024);        // 64 KB
    float*  sacc = (float*)(ws + (size_t)8 * 1024 * 1024 + 65536);

    hipMemsetAsync(sacc, 0, N_ROWS * sizeof(float), stream);
    norm_kernel<<<N_ROWS / 4, 256, 0, stream>>>(A, P, a16, p16t, diag);
    lse_kernel<<<(N_ROWS / BM) * COLSPLIT, 256, 0, stream>>>(a16, p16t, sacc);
    finalize_kernel<<<1, 1024, 0, stream>>>(sacc, diag, out);
}

// Round 13
// 95.293 us; speedup vs baseline: 1.1025x; 1.1025x over previous
//
#include <hip/hip_runtime.h>
#include <hip/hip_bf16.h>

#define N_ROWS 16384
#define DIM 128

constexpr float INV_T = 1.0f / 0.07f;                 // 14.2857...
constexpr float LOG2E = 1.4426950408889634f;
constexpr float C1    = INV_T * LOG2E;                // exp2 scale, folded into A
constexpr float LN2   = 0.69314718055994530942f;

typedef short bf16x8 __attribute__((ext_vector_type(8)));
typedef float f32x16 __attribute__((ext_vector_type(16)));

typedef const __attribute__((address_space(1))) void* gptr1_t;
typedef __attribute__((address_space(3))) void*       sptr3_t;

__device__ __forceinline__ ushort f2bf(float x) {
    unsigned u = __float_as_uint(x);
    u += 0x7fffu + ((u >> 16) & 1u);                  // RTNE
    return (ushort)(u >> 16);
}

// p stored PRE-TILED in B-fragment order, 32-col tiles of 8KB:
//   layout [tile32][kf8][hi2][c31 32]x(8 bf16)   (proven R11)
#define TILE_U16 4096                 /* 32 cols x 128 k = 8 KB           */
#define TILE_BYTES 8192
#define BM 256                        /* rows per block (4 waves x 64)    */
#define WROWS 64
#define COLSPLIT 16
#define COLS_PER (N_ROWS / COLSPLIT)  /* 1024 */
#define NJT (COLS_PER / 32)           /* 32 tiles */

// ---------------------------------------------------------------------------
// Kernel 1: normalize; A scaled by C1 (exp2 fold); P written tiled (32-col);
// exact fp32 diagonal logit; also zeroes sacc (replaces memset dispatch).
// ---------------------------------------------------------------------------
__global__ __launch_bounds__(256) void norm_kernel(
    const float* __restrict__ A, const float* __restrict__ P,
    ushort* __restrict__ a16, ushort* __restrict__ p16t,
    float* __restrict__ diag, float* __restrict__ sacc)
{
    if (threadIdx.x < 4) sacc[blockIdx.x * 4 + threadIdx.x] = 0.f;
    int row  = blockIdx.x * 4 + (threadIdx.x >> 6);
    int lane = threadIdx.x & 63;
    float2 av = *(const float2*)(A + (size_t)row * DIM + lane * 2);
    float2 pv = *(const float2*)(P + (size_t)row * DIM + lane * 2);
    float ssa = av.x * av.x + av.y * av.y;
    float ssp = pv.x * pv.x + pv.y * pv.y;
    float dp  = av.x * pv.x + av.y * pv.y;
    #pragma unroll
    for (int m = 1; m < 64; m <<= 1) {
        ssa += __shfl_xor(ssa, m);
        ssp += __shfl_xor(ssp, m);
        dp  += __shfl_xor(dp,  m);
    }
    float ra = 1.0f / fmaxf(sqrtf(ssa), 1e-12f);
    float rp = 1.0f / fmaxf(sqrtf(ssp), 1e-12f);
    if (lane == 0) diag[row] = dp * ra * rp * INV_T;
    float sa = ra * C1;
    ushort2 a2, p2;
    a2.x = f2bf(av.x * sa); a2.y = f2bf(av.y * sa);
    p2.x = f2bf(pv.x * rp); p2.y = f2bf(pv.y * rp);
    *(ushort2*)(a16 + (size_t)row * DIM + lane * 2) = a2;
    // k = 2*lane: kf=lane>>3, hi=(lane>>2)&1, e=2*(lane&3)  (verified map)
    size_t off = (size_t)(row >> 5) * TILE_U16 + (lane >> 3) * 512
               + ((lane >> 2) & 1) * 256 + (row & 31) * 8 + (lane & 3) * 2;
    *(ushort2*)(p16t + off) = p2;
}

// ---------------------------------------------------------------------------
// Kernel 2: per-row sum of exp2(C1*cos - C1) via 32x32x16 bf16 MFMA.
// R11 schedule (counted vmcnt, triple buffer, s_barrier) + ONE change:
// exp/accumulate of tile j DEFERRED to after the MFMA cluster of tile j+1
// (static accE/accO pairs) — the wave issues trans/VALU work of the
// previous tile while the current MFMA chain drains, instead of stalling
// on its own chain's completion.
// Race audit unchanged from R11 (deferral touches only registers).
// REG-CAP DISCIPLINE: (256,2) ONLY — tighter caps spill (R2/R4/R6).
// ---------------------------------------------------------------------------
__global__ __launch_bounds__(256, 2) void lse_kernel(
    const ushort* __restrict__ a16, const ushort* __restrict__ p16t,
    float* __restrict__ s_accum)
{
    __shared__ __attribute__((aligned(16))) ushort btile[3][TILE_U16];

    int colseg = blockIdx.x & (COLSPLIT - 1);   // round-robin -> XCD-pinned
    int rowblk = blockIdx.x / COLSPLIT;
    int wave = threadIdx.x >> 6;
    int lane = threadIdx.x & 63;
    int c31  = lane & 31, hi = lane >> 5;
    int row0 = rowblk * BM + wave * WROWS;

    // A fragments: 2 row-tiles x 8 K-frags (K=16 each), 8 bf16/lane.
    bf16x8 afrag[2][8];
    #pragma unroll
    for (int t = 0; t < 2; ++t)
        #pragma unroll
        for (int kf = 0; kf < 8; ++kf)
            afrag[t][kf] = *(const bf16x8*)(
                a16 + (size_t)(row0 + t * 32 + c31) * DIM + kf * 16 + hi * 8);

    f32x16 cinit;
    #pragma unroll
    for (int r = 0; r < 16; ++r) cinit[r] = -C1;

    float s0[16], s1[16];
    #pragma unroll
    for (int r = 0; r < 16; ++r) { s0[r] = 0.f; s1[r] = 0.f; }

    const char* seg = (const char*)p16t + (size_t)colseg * NJT * TILE_BYTES;
    char* lds = (char*)&btile[0][0];
    // this wave stages chunks {2*wave, 2*wave+1} of each 8-chunk tile
    int choff = wave * 2048 + lane * 16;

    auto STAGE = [&](int t, int buf) {
        const char* src = seg + (size_t)t * TILE_BYTES + choff;
        char* dst = lds + buf * TILE_BYTES + choff;
        __builtin_amdgcn_global_load_lds((gptr1_t)src, (sptr3_t)dst, 16, 0, 0);
        __builtin_amdgcn_global_load_lds((gptr1_t)(src + 1024),
                                         (sptr3_t)(dst + 1024), 16, 0, 0);
    };

    auto MFMA_TILE = [&](int buf, f32x16& o0, f32x16& o1) {
        const ushort* tb = (const ushort*)(lds + buf * TILE_BYTES) + lane * 8;
        bf16x8 b0 = *(const bf16x8*)(tb);
        __builtin_amdgcn_s_setprio(1);
        o0 = __builtin_amdgcn_mfma_f32_32x32x16_bf16(afrag[0][0], b0, cinit, 0, 0, 0);
        o1 = __builtin_amdgcn_mfma_f32_32x32x16_bf16(afrag[1][0], b0, cinit, 0, 0, 0);
        #pragma unroll
        for (int kf = 1; kf < 8; ++kf) {
            bf16x8 b = *(const bf16x8*)(tb + kf * 512);
            o0 = __builtin_amdgcn_mfma_f32_32x32x16_bf16(afrag[0][kf], b, o0, 0, 0, 0);
            o1 = __builtin_amdgcn_mfma_f32_32x32x16_bf16(afrag[1][kf], b, o1, 0, 0, 0);
        }
        __builtin_amdgcn_s_setprio(0);
    };

    auto EXPADD = [&](const f32x16& a0, const f32x16& a1) {
        #pragma unroll
        for (int r = 0; r < 16; ++r) {
            s0[r] += __builtin_amdgcn_exp2f(a0[r]);
            s1[r] += __builtin_amdgcn_exp2f(a1[r]);
        }
    };

    f32x16 accE0, accE1, accO0, accO1;

    // prologue: stage tiles 0 (buf0) and 1 (buf1); 4 loads outstanding
    STAGE(0, 0);
    STAGE(1, 1);

    // jt=0: consume t0 -> accE (no deferred exp yet)
    asm volatile("s_waitcnt vmcnt(2)" ::: "memory");   // t0 landed
    __builtin_amdgcn_s_barrier();
    __builtin_amdgcn_sched_barrier(0);
    STAGE(2, 2);
    MFMA_TILE(0, accE0, accE1);

    // jt = 2m+1 (accO, flush accE) ; jt = 2m+2 (accE, flush accO)
    for (int m = 0; m < 15; ++m) {
        int jt1 = 2 * m + 1;
        asm volatile("s_waitcnt vmcnt(2)" ::: "memory"); // t_{jt1} landed
        __builtin_amdgcn_s_barrier();
        __builtin_amdgcn_sched_barrier(0);
        STAGE(jt1 + 2, (jt1 + 2) % 3);
        MFMA_TILE(jt1 % 3, accO0, accO1);
        EXPADD(accE0, accE1);                            // tile jt1-1

        int jt2 = 2 * m + 2;
        asm volatile("s_waitcnt vmcnt(2)" ::: "memory"); // t_{jt2} landed
        __builtin_amdgcn_s_barrier();
        __builtin_amdgcn_sched_barrier(0);
        if (jt2 + 2 < NJT) STAGE(jt2 + 2, (jt2 + 2) % 3);
        MFMA_TILE(jt2 % 3, accE0, accE1);
        EXPADD(accO0, accO1);                            // tile jt2-1
    }

    // jt=31: consume t31 -> accO, flush accE, then flush accO
    asm volatile("s_waitcnt vmcnt(0)" ::: "memory");
    __builtin_amdgcn_s_barrier();
    __builtin_amdgcn_sched_barrier(0);
    MFMA_TILE(31 % 3, accO0, accO1);
    EXPADD(accE0, accE1);                                // tile 30
    EXPADD(accO0, accO1);                                // tile 31

    // reduce each row's 32 column-lanes (within each 32-lane half), one atomic
    #pragma unroll
    for (int t = 0; t < 2; ++t)
        #pragma unroll
        for (int r = 0; r < 16; ++r) {
            float v = (t ? s1[r] : s0[r]);
            v += __shfl_xor(v, 1);
            v += __shfl_xor(v, 2);
            v += __shfl_xor(v, 4);
            v += __shfl_xor(v, 8);
            v += __shfl_xor(v, 16);
            if (c31 == 0)
                atomicAdd(&s_accum[row0 + t * 32 + (r & 3) + 8 * (r >> 2) + 4 * hi], v);
        }
}

// ---------------------------------------------------------------------------
// Kernel 3: loss = mean( ln(s_i) + 1/T - diag_i )
// ---------------------------------------------------------------------------
__global__ __launch_bounds__(1024) void finalize_kernel(
    const float* __restrict__ s_acc, const float* __restrict__ diag,
    float* __restrict__ out)
{
    float acc = 0.f;
    int t = threadIdx.x;
    #pragma unroll
    for (int i = 0; i < 4; ++i) {
        int idx = (i * 1024 + t) * 4;
        float4 sv = *(const float4*)(s_acc + idx);
        float4 dv = *(const float4*)(diag + idx);
        acc += __builtin_amdgcn_logf(sv.x) * LN2 + INV_T - dv.x;
        acc += __builtin_amdgcn_logf(sv.y) * LN2 + INV_T - dv.y;
        acc += __builtin_amdgcn_logf(sv.z) * LN2 + INV_T - dv.z;
        acc += __builtin_amdgcn_logf(sv.w) * LN2 + INV_T - dv.w;
    }
    #pragma unroll
    for (int m = 1; m < 64; m <<= 1) acc += __shfl_xor(acc, m);
    __shared__ float wsum[16];
    if ((t & 63) == 0) wsum[t >> 6] = acc;
    __syncthreads();
    if (t == 0) {
        float r = 0.f;
        #pragma unroll
        for (int i = 0; i < 16; ++i) r += wsum[i];
        out[0] = r / (float)N_ROWS;
    }
}

// ---------------------------------------------------------------------------
extern "C" void kernel_launch(void* const* d_in, const int* in_sizes, int n_in,
                              void* d_out, int out_size, void* d_ws, size_t ws_size,
                              hipStream_t stream)
{
    const float* A = (const float*)d_in[0];
    const float* P = (const float*)d_in[1];
    float* out = (float*)d_out;

    char* ws = (char*)d_ws;
    ushort* a16  = (ushort*)ws;                                   // 4 MB
    ushort* p16t = (ushort*)(ws + (size_t)4 * 1024 * 1024);       // 4 MB tiled
    float*  diag = (float*)(ws + (size_t)8 * 1024 * 1024);        // 64 KB
    float*  sacc = (float*)(ws + (size_t)8 * 1024 * 1024 + 65536);

    norm_kernel<<<N_ROWS / 4, 256, 0, stream>>>(A, P, a16, p16t, diag, sacc);
    lse_kernel<<<(N_ROWS / BM) * COLSPLIT, 256, 0, stream>>>(a16, p16t, sacc);
    finalize_kernel<<<1, 1024, 0, stream>>>(sacc, diag, out);
}

// Round 14
// 62.855 us; speedup vs baseline: 1.6714x; 1.5161x over previous
//
#include <hip/hip_runtime.h>
#include <hip/hip_bf16.h>

#define N_ROWS 16384
#define DIM 128

constexpr float INV_T = 1.0f / 0.07f;                 // 14.2857...
constexpr float LOG2E = 1.4426950408889634f;
constexpr float C1    = INV_T * LOG2E;                // 20.6099  (exp2 scale)
constexpr float SOP   = 4.5398160f;                   // sqrt(C1), split per operand
constexpr float LN2   = 0.69314718055994530942f;

typedef int   v4i    __attribute__((ext_vector_type(4)));
typedef int   v8i    __attribute__((ext_vector_type(8)));
typedef float f32x16 __attribute__((ext_vector_type(16)));

typedef const __attribute__((address_space(1))) void* gptr1_t;
typedef __attribute__((address_space(3))) void*       sptr3_t;

// p8 PRE-TILED as the B-operand of mfma_scale_f32_32x32x64_f8f6f4:
// one 32-col tile = 4KB contiguous: [c2][h2][b2][col32][16B]
//   col j -> tile=j>>5, col=j&31 ; k -> c=k>>6, h=(k>>5)&1, b=(k>>4)&1, o=k&15
// Lane l reads col=l&31, k=64c+32(l>>5)+0..31 => two ds_read_b128 at
//   c*2048 + (l>>5)*1024 + {0,512} + (l&31)*16   (16B lane stride: conflict-free)
#define TILE_BYTES 4096
#define BM 256                        /* rows per block (4 waves x 64)    */
#define WROWS 64
#define COLSPLIT 16
#define COLS_PER (N_ROWS / COLSPLIT)  /* 1024 */
#define NJT (COLS_PER / 32)           /* 32 tiles */

// ---------------------------------------------------------------------------
// Kernel 1: normalize; both operands scaled by sqrt(C1); fp8 e4m3 outputs
// (A row-major, P tiled); exact fp32 diagonal logit; zeroes sacc.
// ---------------------------------------------------------------------------
__global__ __launch_bounds__(256) void norm_kernel(
    const float* __restrict__ A, const float* __restrict__ P,
    ushort* __restrict__ a8u, ushort* __restrict__ p8u,
    float* __restrict__ diag, float* __restrict__ sacc)
{
    if (threadIdx.x < 4) sacc[blockIdx.x * 4 + threadIdx.x] = 0.f;
    int row  = blockIdx.x * 4 + (threadIdx.x >> 6);
    int lane = threadIdx.x & 63;
    float2 av = *(const float2*)(A + (size_t)row * DIM + lane * 2);
    float2 pv = *(const float2*)(P + (size_t)row * DIM + lane * 2);
    float ssa = av.x * av.x + av.y * av.y;
    float ssp = pv.x * pv.x + pv.y * pv.y;
    float dp  = av.x * pv.x + av.y * pv.y;
    #pragma unroll
    for (int m = 1; m < 64; m <<= 1) {
        ssa += __shfl_xor(ssa, m);
        ssp += __shfl_xor(ssp, m);
        dp  += __shfl_xor(dp,  m);
    }
    float ra = 1.0f / fmaxf(sqrtf(ssa), 1e-12f);
    float rp = 1.0f / fmaxf(sqrtf(ssp), 1e-12f);
    if (lane == 0) diag[row] = dp * ra * rp * INV_T;
    float sa = ra * SOP, sp = rp * SOP;
    int apk = __builtin_amdgcn_cvt_pk_fp8_f32(av.x * sa, av.y * sa, 0, false);
    int ppk = __builtin_amdgcn_cvt_pk_fp8_f32(pv.x * sp, pv.y * sp, 0, false);
    // a8 row-major: byte k=2*lane -> ushort idx row*64+lane
    a8u[(size_t)row * 64 + lane] = (ushort)apk;
    // p8 tiled: k=2*lane -> c=l>>5, h=(l>>4)&1, b=(l>>3)&1, o=2l&15 (ushort idx /2)
    size_t off = (size_t)(row >> 5) * 2048 + (lane >> 5) * 1024
               + ((lane >> 4) & 1) * 512 + ((lane >> 3) & 1) * 256
               + (row & 31) * 8 + (lane & 7);
    p8u[off] = (ushort)ppk;
}

// ---------------------------------------------------------------------------
// Kernel 2: per-row sum of exp2(C1*cos - C1) via MX-fp8 32x32x64 MFMA
// (identity scales 0x7f7f7f7f -> pure fp8 e4m3 matmul at 2x bf16 rate).
// R11-proven schedule: counted vmcnt (never 0 mid-loop), triple-buffered
// 4KB tiles, one s_barrier per tile, setprio around the MFMA cluster.
// Per wave-tile: 4 ds_read_b128 + 4 mfma_scale + 32 exp2.
// REG-CAP DISCIPLINE: (256,2) ONLY — tighter caps spill (R2/R4/R6).
// ---------------------------------------------------------------------------
__global__ __launch_bounds__(256, 2) void lse_kernel(
    const ushort* __restrict__ a8u, const ushort* __restrict__ p8u,
    float* __restrict__ s_accum)
{
    __shared__ __attribute__((aligned(16))) char btile[3][TILE_BYTES];

    int colseg = blockIdx.x & (COLSPLIT - 1);   // round-robin -> XCD-pinned
    int rowblk = blockIdx.x / COLSPLIT;
    int wave = threadIdx.x >> 6;
    int lane = threadIdx.x & 63;
    int c31  = lane & 31, hi = lane >> 5;
    int row0 = rowblk * BM + wave * WROWS;

    // A fragments: 2 row-tiles x 2 K-chunks, 32B/lane each (v8i), row-major a8
    const char* a8 = (const char*)a8u;
    v8i afA0 = *(const v8i*)(a8 + (size_t)(row0 + c31) * 128 +       hi * 32);
    v8i afA1 = *(const v8i*)(a8 + (size_t)(row0 + c31) * 128 + 64  + hi * 32);
    v8i afB0 = *(const v8i*)(a8 + (size_t)(row0 + 32 + c31) * 128 +      hi * 32);
    v8i afB1 = *(const v8i*)(a8 + (size_t)(row0 + 32 + c31) * 128 + 64 + hi * 32);

    f32x16 cinit;
    #pragma unroll
    for (int r = 0; r < 16; ++r) cinit[r] = -C1;

    float s0[16], s1[16];
    #pragma unroll
    for (int r = 0; r < 16; ++r) { s0[r] = 0.f; s1[r] = 0.f; }

    const char* seg = (const char*)p8u + (size_t)colseg * NJT * TILE_BYTES;
    char* lds = (char*)&btile[0][0];
    int choff = wave * 1024 + lane * 16;   // each wave stages 1KB of the 4KB tile

    auto STAGE = [&](int t, int buf) {
        __builtin_amdgcn_global_load_lds(
            (gptr1_t)(seg + (size_t)t * TILE_BYTES + choff),
            (sptr3_t)(lds + buf * TILE_BYTES + choff), 16, 0, 0);
    };

    int rdoff = hi * 1024 + c31 * 16;

    f32x16 acc0, acc1;

    // prologue: stage tiles 0,1 -> bufs 0,1 (one load each)
    STAGE(0, 0);
    STAGE(1, 1);

    for (int jt = 0; jt < NJT; ++jt) {
        if (jt < NJT - 1) asm volatile("s_waitcnt vmcnt(1)" ::: "memory");
        else              asm volatile("s_waitcnt vmcnt(0)" ::: "memory");
        __builtin_amdgcn_s_barrier();
        __builtin_amdgcn_sched_barrier(0);

        if (jt + 2 < NJT) STAGE(jt + 2, (jt + 2) % 3);

        const char* tb = lds + (jt % 3) * TILE_BYTES;
        v4i x0 = *(const v4i*)(tb + rdoff);
        v4i y0 = *(const v4i*)(tb + rdoff + 512);
        v4i x1 = *(const v4i*)(tb + 2048 + rdoff);
        v4i y1 = *(const v4i*)(tb + 2048 + rdoff + 512);
        v8i b0, b1;
        #pragma unroll
        for (int j = 0; j < 4; ++j) {
            b0[j] = x0[j]; b0[4 + j] = y0[j];
            b1[j] = x1[j]; b1[4 + j] = y1[j];
        }

        __builtin_amdgcn_s_setprio(1);
        acc0 = __builtin_amdgcn_mfma_scale_f32_32x32x64_f8f6f4(
            afA0, b0, cinit, 0, 0, 0, 0x7f7f7f7f, 0, 0x7f7f7f7f);
        acc1 = __builtin_amdgcn_mfma_scale_f32_32x32x64_f8f6f4(
            afB0, b0, cinit, 0, 0, 0, 0x7f7f7f7f, 0, 0x7f7f7f7f);
        acc0 = __builtin_amdgcn_mfma_scale_f32_32x32x64_f8f6f4(
            afA1, b1, acc0, 0, 0, 0, 0x7f7f7f7f, 0, 0x7f7f7f7f);
        acc1 = __builtin_amdgcn_mfma_scale_f32_32x32x64_f8f6f4(
            afB1, b1, acc1, 0, 0, 0, 0x7f7f7f7f, 0, 0x7f7f7f7f);
        __builtin_amdgcn_s_setprio(0);

        #pragma unroll
        for (int r = 0; r < 16; ++r) {
            s0[r] += __builtin_amdgcn_exp2f(acc0[r]);
            s1[r] += __builtin_amdgcn_exp2f(acc1[r]);
        }
    }

    // reduce each row's 32 column-lanes (within each 32-lane half), one atomic
    // C/D layout identical to bf16 32x32 (dtype-independent, m121-128)
    #pragma unroll
    for (int t = 0; t < 2; ++t)
        #pragma unroll
        for (int r = 0; r < 16; ++r) {
            float v = (t ? s1[r] : s0[r]);
            v += __shfl_xor(v, 1);
            v += __shfl_xor(v, 2);
            v += __shfl_xor(v, 4);
            v += __shfl_xor(v, 8);
            v += __shfl_xor(v, 16);
            if (c31 == 0)
                atomicAdd(&s_accum[row0 + t * 32 + (r & 3) + 8 * (r >> 2) + 4 * hi], v);
        }
}

// ---------------------------------------------------------------------------
// Kernel 3: loss = mean( ln(s_i) + 1/T - diag_i )
// ---------------------------------------------------------------------------
__global__ __launch_bounds__(1024) void finalize_kernel(
    const float* __restrict__ s_acc, const float* __restrict__ diag,
    float* __restrict__ out)
{
    float acc = 0.f;
    int t = threadIdx.x;
    #pragma unroll
    for (int i = 0; i < 4; ++i) {
        int idx = (i * 1024 + t) * 4;
        float4 sv = *(const float4*)(s_acc + idx);
        float4 dv = *(const float4*)(diag + idx);
        acc += __builtin_amdgcn_logf(sv.x) * LN2 + INV_T - dv.x;
        acc += __builtin_amdgcn_logf(sv.y) * LN2 + INV_T - dv.y;
        acc += __builtin_amdgcn_logf(sv.z) * LN2 + INV_T - dv.z;
        acc += __builtin_amdgcn_logf(sv.w) * LN2 + INV_T - dv.w;
    }
    #pragma unroll
    for (int m = 1; m < 64; m <<= 1) acc += __shfl_xor(acc, m);
    __shared__ float wsum[16];
    if ((t & 63) == 0) wsum[t >> 6] = acc;
    __syncthreads();
    if (t == 0) {
        float r = 0.f;
        #pragma unroll
        for (int i = 0; i < 16; ++i) r += wsum[i];
        out[0] = r / (float)N_ROWS;
    }
}

// ---------------------------------------------------------------------------
extern "C" void kernel_launch(void* const* d_in, const int* in_sizes, int n_in,
                              void* d_out, int out_size, void* d_ws, size_t ws_size,
                              hipStream_t stream)
{
    const float* A = (const float*)d_in[0];
    const float* P = (const float*)d_in[1];
    float* out = (float*)d_out;

    char* ws = (char*)d_ws;
    ushort* a8u  = (ushort*)ws;                                   // 2 MB fp8
    ushort* p8u  = (ushort*)(ws + (size_t)2 * 1024 * 1024);       // 2 MB fp8 tiled
    float*  diag = (float*)(ws + (size_t)4 * 1024 * 1024);        // 64 KB
    float*  sacc = (float*)(ws + (size_t)4 * 1024 * 1024 + 65536);

    norm_kernel<<<N_ROWS / 4, 256, 0, stream>>>(A, P, a8u, p8u, diag, sacc);
    lse_kernel<<<(N_ROWS / BM) * COLSPLIT, 256, 0, stream>>>(a8u, p8u, sacc);
    finalize_kernel<<<1, 1024, 0, stream>>>(sacc, diag, out);
}